// Round 1
// baseline (876.793 us; speedup 1.0000x reference)
//
#include <hip/hip_runtime.h>
#include <hip/hip_bf16.h>
#include <cstdint>
#include <cstddef>

#define ATTN_OFF (2u*2048u*2048u)   // adjacency comes first in d_out

// ---------------------------------------------------------------------------
// Low-rank projection: out = (in @ u) @ v, f64 math.
// in: [4096, 256] (InT), u: [256,64] f32, v: [64,256] f32.
// TRANS=true stores out transposed per-(b,h) slab: out[((b*8+h)*32+d)*2048 + m]
// ---------------------------------------------------------------------------
template <typename InT, typename OutT, bool TRANS>
__global__ __launch_bounds__(256) void lowrank_kernel(
    const InT* __restrict__ in, const float* __restrict__ u,
    const float* __restrict__ v, OutT* __restrict__ out) {
  __shared__ double mid[4][64];
  int tid = threadIdx.x;
  int rr = tid >> 6;          // 0..3 (row within block)
  int j  = tid & 63;          // 0..63
  int row = blockIdx.x * 4 + rr;

  const InT* inr = in + (size_t)row * 256;
  double acc = 0.0;
#pragma unroll 8
  for (int kk = 0; kk < 256; ++kk)
    acc = fma((double)inr[kk], (double)u[kk * 64 + j], acc);
  mid[rr][j] = acc;
  __syncthreads();

#pragma unroll
  for (int cc = 0; cc < 4; ++cc) {
    int col = j + 64 * cc;
    double o = 0.0;
#pragma unroll 8
    for (int r = 0; r < 64; ++r)
      o = fma(mid[rr][r], (double)v[r * 256 + col], o);
    if (TRANS) {
      int b = row >> 11, m = row & 2047, hh = col >> 5, d = col & 31;
      out[(((size_t)(b * 8 + hh)) * 32 + d) * 2048 + m] = (OutT)o;
    } else {
      out[(size_t)row * 256 + col] = (OutT)o;
    }
  }
}

// ---------------------------------------------------------------------------
// Exact per-row top-k (k=32) kth-value via LDS histogram + candidate ranking.
// All operations are within one 32-lane group (one wave): no __syncthreads
// needed (LDS ops of a wave execute in order; compiler inserts lgkmcnt waits).
// ---------------------------------------------------------------------------
__device__ __forceinline__ float find_kth(const float (&s)[64], float mx,
                                          int c, int pr,
                                          unsigned* hrow, float* crow,
                                          unsigned* cn,
                                          volatile float* kslot) {
  // zero histogram / counters (by this row's own 32 lanes)
#pragma unroll
  for (int i = 0; i < 8; ++i) hrow[c * 8 + i] = 0u;
  if (c == 0) { *cn = 0u; *kslot = -1e30f; }

  // fill histogram: bucket = floor((mx - s) * 16), clamped to 255
#pragma unroll
  for (int jj = 0; jj < 64; ++jj) {
    int bb = (int)((mx - s[jj]) * 16.0f);
    bb = bb > 255 ? 255 : bb;
    atomicAdd(&hrow[bb], 1u);
  }

  // scan: find bucket B where cumulative count crosses 32, and count_before
  unsigned cnt8 = 0;
#pragma unroll
  for (int i = 0; i < 8; ++i) cnt8 += hrow[c * 8 + i];
  unsigned pre = cnt8;
#pragma unroll
  for (int off = 1; off < 32; off <<= 1) {
    unsigned t = __shfl_up(pre, (unsigned)off, 32);
    if (c >= off) pre += t;
  }
  unsigned excl = pre - cnt8;
  bool flag = (excl < 32u) && (pre >= 32u);
  unsigned long long bal = __ballot(flag);
  unsigned grp = (unsigned)(bal >> (pr * 32));
  int src = __ffs(grp) - 1 + pr * 32;
  int Bm = 255; unsigned cbm = 0;
  if (flag) {
    unsigned cum = excl;
#pragma unroll
    for (int i = 0; i < 8; ++i) {
      unsigned hv = hrow[c * 8 + i];
      if (cum < 32u && cum + hv >= 32u) { Bm = c * 8 + i; cbm = cum; }
      cum += hv;
    }
  }
  int B = __shfl(Bm, src, 64);
  unsigned cbefore = (unsigned)__shfl((int)cbm, src, 64);
  unsigned need = 32u - cbefore;

  // collect candidates in bucket B
#pragma unroll
  for (int jj = 0; jj < 64; ++jj) {
    int bb = (int)((mx - s[jj]) * 16.0f);
    bb = bb > 255 ? 255 : bb;
    if (bb == B) {
      unsigned idx = atomicAdd(cn, 1u);
      if (idx < 128u) crow[idx] = s[jj];
    }
  }
  unsigned n0 = *cn;
  n0 = n0 > 128u ? 128u : n0;

  // stable-rank selection: kth = (need)-th largest among candidates
  for (unsigned ci = (unsigned)c; ci < n0; ci += 32u) {
    float x = crow[ci];
    unsigned r = 0;
    for (unsigned jj = 0; jj < n0; ++jj) {
      float y = crow[jj];
      r += (y > x || (y == x && jj < ci)) ? 1u : 0u;
    }
    if (r == need - 1u) *kslot = x;
  }
  return *kslot;
}

__device__ __forceinline__ void softmax_write(float (&s)[64], float mx,
                                              float kth, int c,
                                              float* __restrict__ orow) {
  float z = 0.0f;
#pragma unroll
  for (int jj = 0; jj < 64; ++jj) {
    float p = (s[jj] >= kth) ? expf(s[jj] - mx) : 0.0f;
    s[jj] = p;
    z += p;
  }
#pragma unroll
  for (int off = 16; off >= 1; off >>= 1) z += __shfl_xor(z, (unsigned)off, 32);
  float rz = 1.0f / z;
#pragma unroll
  for (int jj = 0; jj < 64; ++jj)
    orow[(jj >> 2) * 128 + (jj & 3) * 32 + c] = s[jj] * rz;
}

// ---------------------------------------------------------------------------
// Fused scores (f64) + exact top-32 + softmax. One block = 16 rows of one
// (b,h) slab. Each thread: 2 rows x 64 m-columns (scores in registers).
// ---------------------------------------------------------------------------
__global__ __launch_bounds__(256, 2) void attn_kernel(
    const double* __restrict__ q, const double* __restrict__ kt,
    float* __restrict__ attn) {
  __shared__ __align__(16) double q_lds[16][32];
  __shared__ __align__(16) double k_tile[32][128];
  __shared__ unsigned hist[16][256];
  __shared__ float cand[16][128];
  __shared__ unsigned ccnt[16];
  __shared__ volatile float kth_s[16];

  int tid = threadIdx.x;
  int bx = blockIdx.x;
  int slab = bx >> 7;       // b*8 + h
  int rowtile = bx & 127;
  int b = slab >> 3, hh = slab & 7;
  int lane = tid & 63, w = tid >> 6;
  int c = lane & 31, pr = lane >> 5;
  int r0loc = w * 4 + pr * 2;   // rows r0loc, r0loc+1 of this block's 16

  // stage q rows [16][32] f64
  {
    int rloc = tid >> 4, dp = tid & 15;
    int n = rowtile * 16 + rloc;
    double2 qv = *(const double2*)(q + ((size_t)(b * 2048 + n)) * 256 +
                                   hh * 32 + dp * 2);
    ((double2*)q_lds)[tid] = qv;
  }

  const double* kslab = kt + (size_t)slab * (32 * 2048);
  float s0[64], s1[64];
  double acc0[4] = {0, 0, 0, 0}, acc1[4] = {0, 0, 0, 0};
  float mx0 = -1e30f, mx1 = -1e30f;
  const double INV = 0.17677669529663688110021109052621;  // 1/sqrt(32)

#pragma unroll
  for (int t = 0; t < 16; ++t) {
    __syncthreads();
    // stage k tile: [32 d][128 m] f64 as double2, coalesced both sides
#pragma unroll
    for (int jj = 0; jj < 8; ++jj) {
      int p = tid + 256 * jj;
      double2 val = *(const double2*)(kslab + (size_t)(p >> 6) * 2048 +
                                      t * 128 + (p & 63) * 2);
      ((double2*)k_tile)[p] = val;
    }
    __syncthreads();
#pragma unroll
    for (int dq = 0; dq < 4; ++dq) {
      double qa[8], qb[8];
#pragma unroll
      for (int dd = 0; dd < 8; ++dd) {
        qa[dd] = q_lds[r0loc][dq * 8 + dd];
        qb[dd] = q_lds[r0loc + 1][dq * 8 + dd];
      }
#pragma unroll
      for (int mi = 0; mi < 4; ++mi) {
        int ml = c + 32 * mi;
#pragma unroll
        for (int dd = 0; dd < 8; ++dd) {
          double kv = k_tile[dq * 8 + dd][ml];
          acc0[mi] = fma(qa[dd], kv, acc0[mi]);
          acc1[mi] = fma(qb[dd], kv, acc1[mi]);
        }
      }
    }
#pragma unroll
    for (int mi = 0; mi < 4; ++mi) {
      float f0 = (float)(acc0[mi] * INV);
      float f1 = (float)(acc1[mi] * INV);
      s0[t * 4 + mi] = f0;
      s1[t * 4 + mi] = f1;
      mx0 = fmaxf(mx0, f0);
      mx1 = fmaxf(mx1, f1);
      acc0[mi] = 0.0;
      acc1[mi] = 0.0;
    }
  }

  // row max across the 32 m-lanes
#pragma unroll
  for (int off = 16; off >= 1; off >>= 1) {
    mx0 = fmaxf(mx0, __shfl_xor(mx0, (unsigned)off, 32));
    mx1 = fmaxf(mx1, __shfl_xor(mx1, (unsigned)off, 32));
  }

  int rl0 = r0loc, rl1 = r0loc + 1;
  float kth0 = find_kth(s0, mx0, c, pr, &hist[rl0][0], &cand[rl0][0],
                        &ccnt[rl0], &kth_s[rl0]);
  float kth1 = find_kth(s1, mx1, c, pr, &hist[rl1][0], &cand[rl1][0],
                        &ccnt[rl1], &kth_s[rl1]);

  int n0g = rowtile * 16 + rl0;
  float* o0 = attn + ((size_t)slab * 2048 + n0g) * 2048;
  float* o1 = attn + ((size_t)slab * 2048 + n0g + 1) * 2048;
  softmax_write(s0, mx0, kth0, c, o0);
  softmax_write(s1, mx1, kth1, c, o1);
}

// ---------------------------------------------------------------------------
// PV: out[b,n, h*32+dh] = sum_m attn[b,h,n,m] * v[b,m, h*32+dh]  (fp32)
// block = 32 rows of one slab; thread = (r8, dh), 4 rows each.
// ---------------------------------------------------------------------------
__global__ __launch_bounds__(256) void pv_kernel(
    const float* __restrict__ attn, const float* __restrict__ v,
    float* __restrict__ out) {
  __shared__ float a_lds[32][129];
  __shared__ float v_lds[128][33];
  int tid = threadIdx.x;
  int slab = blockIdx.x >> 6;
  int rt = blockIdx.x & 63;
  int b = slab >> 3, hh = slab & 7;
  int r8 = tid >> 5, dh = tid & 31;

  const float* aslab =
      attn + (size_t)slab * 2048 * 2048 + (size_t)rt * 32 * 2048;
  const float* vbase = v + (size_t)b * 2048 * 256 + hh * 32;
  float acc[4] = {0, 0, 0, 0};

  for (int mt = 0; mt < 16; ++mt) {
    __syncthreads();
#pragma unroll
    for (int jj = 0; jj < 16; ++jj) {
      int e = tid + 256 * jj;
      a_lds[e >> 7][e & 127] =
          aslab[(size_t)(e >> 7) * 2048 + mt * 128 + (e & 127)];
    }
#pragma unroll
    for (int jj = 0; jj < 16; ++jj) {
      int e = tid + 256 * jj;
      v_lds[e >> 5][e & 31] =
          vbase[(size_t)(mt * 128 + (e >> 5)) * 256 + (e & 31)];
    }
    __syncthreads();
#pragma unroll 8
    for (int mm = 0; mm < 128; ++mm) {
      float vv = v_lds[mm][dh];
      acc[0] = fmaf(a_lds[r8 * 4 + 0][mm], vv, acc[0]);
      acc[1] = fmaf(a_lds[r8 * 4 + 1][mm], vv, acc[1]);
      acc[2] = fmaf(a_lds[r8 * 4 + 2][mm], vv, acc[2]);
      acc[3] = fmaf(a_lds[r8 * 4 + 3][mm], vv, acc[3]);
    }
  }
#pragma unroll
  for (int i = 0; i < 4; ++i) {
    int n = rt * 32 + r8 * 4 + i;
    out[((size_t)(b * 2048 + n)) * 256 + hh * 32 + dh] = acc[i];
  }
}

// ---------------------------------------------------------------------------
// adjacency = sigmoid(el @ el^T), zero diagonal.  fp32 GEMM-NT, 64x64 tiles.
// ---------------------------------------------------------------------------
__global__ __launch_bounds__(256) void adj_kernel(const float* __restrict__ el,
                                                  float* __restrict__ adj) {
  __shared__ float a_lds[64][33];
  __shared__ float b_lds[64][33];
  int tid = threadIdx.x;
  int b = blockIdx.z, rt = blockIdx.y, ct = blockIdx.x;
  const float* elb = el + (size_t)b * 2048 * 256;
  int tr = tid >> 4, tc = tid & 15;
  float acc[4][4] = {};

  for (int kt = 0; kt < 8; ++kt) {
    __syncthreads();
#pragma unroll
    for (int jj = 0; jj < 8; ++jj) {
      int e = tid + 256 * jj;
      int r = e >> 5, d = e & 31;
      a_lds[r][d] = elb[(size_t)(rt * 64 + r) * 256 + kt * 32 + d];
      b_lds[r][d] = elb[(size_t)(ct * 64 + r) * 256 + kt * 32 + d];
    }
    __syncthreads();
#pragma unroll
    for (int kk = 0; kk < 32; ++kk) {
      float va[4], vb[4];
#pragma unroll
      for (int i = 0; i < 4; ++i) {
        va[i] = a_lds[tr * 4 + i][kk];
        vb[i] = b_lds[tc * 4 + i][kk];
      }
#pragma unroll
      for (int i = 0; i < 4; ++i)
#pragma unroll
        for (int j2 = 0; j2 < 4; ++j2)
          acc[i][j2] = fmaf(va[i], vb[j2], acc[i][j2]);
    }
  }
#pragma unroll
  for (int i = 0; i < 4; ++i) {
    int rg = rt * 64 + tr * 4 + i;
#pragma unroll
    for (int j2 = 0; j2 < 4; ++j2) {
      int cg = ct * 64 + tc * 4 + j2;
      float sg = 1.0f / (1.0f + expf(-acc[i][j2]));
      if (rg == cg) sg = 0.0f;
      adj[((size_t)b * 2048 + rg) * 2048 + cg] = sg;
    }
  }
}

// ---------------------------------------------------------------------------
extern "C" void kernel_launch(void* const* d_in, const int* in_sizes, int n_in,
                              void* d_out, int out_size, void* d_ws,
                              size_t ws_size, hipStream_t stream) {
  const float* x    = (const float*)d_in[0];
  const float* ne_u = (const float*)d_in[1];
  const float* ne_v = (const float*)d_in[2];
  const float* wq_u = (const float*)d_in[3];
  const float* wq_v = (const float*)d_in[4];
  const float* wk_u = (const float*)d_in[5];
  const float* wk_v = (const float*)d_in[6];
  const float* wv_u = (const float*)d_in[7];
  const float* wv_v = (const float*)d_in[8];
  const float* wo_u = (const float*)d_in[9];
  const float* wo_v = (const float*)d_in[10];
  const float* es_u = (const float*)d_in[11];
  const float* es_v = (const float*)d_in[12];

  float* adj  = (float*)d_out;
  float* attn = adj + (size_t)ATTN_OFF;

  char* ws = (char*)d_ws;
  double* h   = (double*)(ws);                          //  8 MB
  double* qd  = (double*)(ws + ((size_t)8 << 20));      //  8 MB
  double* ktd = (double*)(ws + ((size_t)16 << 20));     //  8 MB
  float*  v   = (float*) (ws + ((size_t)24 << 20));     //  4 MB
  float*  out = (float*) (ws + ((size_t)28 << 20));     //  4 MB
  float*  h2  = (float*) (ws + ((size_t)32 << 20));     //  4 MB
  float*  el  = (float*) (ws + ((size_t)36 << 20));     //  4 MB

  lowrank_kernel<float,  double, false><<<1024, 256, 0, stream>>>(x,  ne_u, ne_v, h);
  lowrank_kernel<double, double, false><<<1024, 256, 0, stream>>>(h,  wq_u, wq_v, qd);
  lowrank_kernel<double, double, true ><<<1024, 256, 0, stream>>>(h,  wk_u, wk_v, ktd);
  lowrank_kernel<double, float,  false><<<1024, 256, 0, stream>>>(h,  wv_u, wv_v, v);

  attn_kernel<<<2048, 256, 0, stream>>>(qd, ktd, attn);
  pv_kernel<<<1024, 256, 0, stream>>>(attn, v, out);

  lowrank_kernel<float, float, false><<<1024, 256, 0, stream>>>(out, wo_u, wo_v, h2);
  lowrank_kernel<float, float, false><<<1024, 256, 0, stream>>>(h2,  es_u, es_v, el);

  adj_kernel<<<dim3(32, 32, 2), 256, 0, stream>>>(el, adj);
}